// Round 7
// baseline (253.531 us; speedup 1.0000x reference)
//
#include <hip/hip_runtime.h>
#include <math.h>

// VQ-VAE quantize on MI355X.
// z: (8, 256, 32, 32) fp32 -> 8192 positions x 256 dims; W: (8192, 256) fp32.
// out: [z_q 2097152 fp32][loss 1 fp32][ind 8192 fp32-encoded ints]
//
// Pipeline: convert (W->bf16 + z->bf16 [pos][k] + loss=0, one launch),
// gemm_argmax (bf16 MFMA; A full-K in LDS behind ONE barrier; B fragments
//              global->register, depth-2 pipeline, ZERO K-loop barriers;
//              packed-key argmax, top-2 per (bn,wn) slot -> part[pos][16]),
// resolve (block per 16 positions: key-decode + rare exact fp32 refine,
//          W-row LDS staging so z_q/loss I/O is fully coalesced).

using short8  = __attribute__((ext_vector_type(8))) short;   // 8 bf16, 4 VGPRs
using floatx4 = __attribute__((ext_vector_type(4))) float;   // MFMA acc

#define MARGIN 0.5f
#define APAD   264    // As row stride in shorts: 528B; b128 reads 2-way = free

__device__ inline unsigned short f2bf(float x) {
    union { float f; unsigned u; } v; v.f = x;
    unsigned r = v.u + 0x7fffu + ((v.u >> 16) & 1u);   // round-to-nearest-even
    return (unsigned short)(r >> 16);
}
__device__ inline unsigned f2ord(float f) {             // monotone float->uint
    unsigned u = __float_as_uint(f);
    return (u & 0x80000000u) ? ~u : (u | 0x80000000u);
}
__device__ inline float ord2f(unsigned o) {
    return __uint_as_float((o & 0x80000000u) ? (o ^ 0x80000000u) : ~o);
}

// ---- pre-pass, fused: blocks <2048 convert W; blocks >=2048 convert z;
//      block 0 also zeroes the loss accumulator (in-stream order => safe) ----
__global__ void convert_kernel(const float* __restrict__ W, const float* __restrict__ z,
                               unsigned short* __restrict__ wb, unsigned short* __restrict__ zb,
                               float* __restrict__ loss) {
    if (blockIdx.x < 2048) {
        if (blockIdx.x == 0 && threadIdx.x == 0) *loss = 0.f;
        int i = blockIdx.x * 256 + threadIdx.x;
        float4 v = *(const float4*)&W[(size_t)i * 4];
        ushort4 o;
        o.x = f2bf(v.x); o.y = f2bf(v.y); o.z = f2bf(v.z); o.w = f2bf(v.w);
        *(ushort4*)&wb[(size_t)i * 4] = o;
    } else {
        __shared__ float tile[64 * 65];
        int blk = blockIdx.x - 2048;
        int b  = blk >> 6;
        int dt = (blk >> 4) & 3;
        int st = blk & 15;
        int dl = threadIdx.x >> 6, sl = threadIdx.x & 63;
#pragma unroll
        for (int i = 0; i < 16; ++i) {
            int d = i * 4 + dl;
            tile[sl * 65 + d] = z[(size_t)b * 262144 + (size_t)(dt * 64 + d) * 1024 + st * 64 + sl];
        }
        __syncthreads();
        int d2 = threadIdx.x & 63, sr = threadIdx.x >> 6;
#pragma unroll
        for (int i = 0; i < 16; ++i) {
            int s = i * 4 + sr;
            int pos = b * 1024 + st * 64 + s;
            zb[(size_t)pos * 256 + dt * 64 + d2] = f2bf(tile[s * 65 + d2]);
        }
    }
}

// ---- main: bf16 MFMA GEMM (128M x 2048N per block, K=256) + fused argmax ----
// grid (64 m-tiles, 4 n-splits), 512 thr (8 waves), 1 block/CU.
// Wave tile 64x64: wm = w>>2, wn = w&3. Panels pc 0..63: nc=pc>>3, kp=pc&7.
// A: full-K LDS tile, ONE barrier, read-only afterwards.
// B: global->register (L2-resident), depth-2 pipeline, compile-time reg
//    indices via full unroll, ZERO barriers in the K-loop.
// Argmax keys: key = (ord(v) & ~8191) | (8191 - n) -> umax == argmax/min-idx.
__global__ __launch_bounds__(512, 2)
void gemm_argmax_kernel(const unsigned short* __restrict__ zb,
                        const unsigned short* __restrict__ wb,
                        uint2* __restrict__ part)
{
    __shared__ unsigned short As[128 * APAD];    // 67.6 KB

    const int t  = threadIdx.x;
    const int bm = blockIdx.x, bn = blockIdx.y;
    const int w  = t >> 6, lane = t & 63;
    const int wm = w >> 2, wn = w & 3;
    const int q  = lane >> 4, l15 = lane & 15;

    // lane's B base: row (bn*2048 + wn*64 + l15), k-offset q*8
    const unsigned short* bwave =
        wb + (size_t)(bn * 2048 + wn * 64 + l15) * 256 + q * 8;

    // depth-2 B pipeline: bf[pc&1][in]; offsets compile-time after unroll
    short8 bf[2][4];
#pragma unroll
    for (int in = 0; in < 4; ++in)   // panel 0: nc=0, kp=0
        bf[0][in] = *(const short8*)(bwave + (size_t)in * 16 * 256);
#pragma unroll
    for (int in = 0; in < 4; ++in)   // panel 1: nc=0, kp=1
        bf[1][in] = *(const short8*)(bwave + (size_t)in * 16 * 256 + 32);

    // stage As: 128 rows x 256 k (coalesced 512B row segments)
    {
        const unsigned short* src = zb + (size_t)bm * 128 * 256;
#pragma unroll
        for (int i = 0; i < 8; ++i) {
            int u = i * 512 + t;
            int row = u >> 5, c8 = (u & 31) * 8;
            *(short8*)(&As[row * APAD + c8]) = *(const short8*)(src + row * 256 + c8);
        }
    }
    __syncthreads();   // the ONLY barrier

    unsigned kkey[4][4];
    floatx4  acc[4][4];
#pragma unroll
    for (int im = 0; im < 4; ++im)
#pragma unroll
        for (int r = 0; r < 4; ++r) {
            kkey[im][r] = 0u;
            floatx4 zz = {0.f, 0.f, 0.f, 0.f};
            acc[im][r] = zz;
        }

#pragma unroll
    for (int pc = 0; pc < 64; ++pc) {
        const int cur = pc & 1, kp = pc & 7;

        short8 af[4];
#pragma unroll
        for (int im = 0; im < 4; ++im)
            af[im] = *(const short8*)&As[(wm * 64 + im * 16 + l15) * APAD + kp * 32 + q * 8];
#pragma unroll
        for (int im = 0; im < 4; ++im)
#pragma unroll
            for (int in = 0; in < 4; ++in)
                acc[im][in] = __builtin_amdgcn_mfma_f32_16x16x32_bf16(
                    af[im], bf[cur][in], acc[im][in], 0, 0, 0);

        // refill the just-consumed buffer with panel pc+2 (compile-time offs)
        if (pc + 2 < 64) {
            const int np = pc + 2, nnc = np >> 3, nkp = np & 7;
            const size_t off = (size_t)nnc * 256 * 256 + nkp * 32;
#pragma unroll
            for (int in = 0; in < 4; ++in)
                bf[cur][in] = *(const short8*)(bwave + off + (size_t)in * 16 * 256);
        }

        // end of a 256-code chunk: tournament over in, one key per (im,r)
        if ((pc & 7) == 7) {
            const int nc = pc >> 3;
            const int nbase = bn * 2048 + nc * 256 + wn * 64 + l15;
#pragma unroll
            for (int im = 0; im < 4; ++im)
#pragma unroll
                for (int r = 0; r < 4; ++r) {
                    float bv = acc[im][0][r];
                    int   bi = nbase;
#pragma unroll
                    for (int in = 1; in < 4; ++in) {
                        float v = acc[im][in][r];
                        int   n = nbase + in * 16;
                        bi = (v > bv) ? n : bi;
                        bv = (v > bv) ? v : bv;
                    }
                    unsigned key = (f2ord(bv) & 0xFFFFE000u) | (8191u - (unsigned)bi);
                    kkey[im][r] = (key > kkey[im][r]) ? key : kkey[im][r];
#pragma unroll
                    for (int in = 0; in < 4; ++in) acc[im][in][r] = 0.f;
                }
        }
    }

    // top-2 key merge across the 16 lanes sharing each m-row
#pragma unroll
    for (int im = 0; im < 4; ++im)
#pragma unroll
        for (int r = 0; r < 4; ++r) {
            unsigned k1 = kkey[im][r], k2 = 0u;
#pragma unroll
            for (int off = 1; off < 16; off <<= 1) {
                unsigned o1 = (unsigned)__shfl_xor((int)k1, off, 64);
                unsigned o2 = (unsigned)__shfl_xor((int)k2, off, 64);
                unsigned hi = (k1 > o1) ? k1 : o1;
                unsigned lo = (k1 > o1) ? o1 : k1;
                unsigned s2 = (k2 > o2) ? k2 : o2;
                k1 = hi;
                k2 = (lo > s2) ? lo : s2;
            }
            if (l15 == 0) {
                int pos = bm * 128 + wm * 64 + im * 16 + q * 4 + r;
                part[(size_t)pos * 16 + bn * 4 + wn] = make_uint2(k1, k2);
            }
        }
}

// ---- resolve: block per 16 positions (512 blocks). Phase 1: wave-parallel
// key-decode argmax over 16 slots, rare exact fp32 refine. Phase 2: stage
// W[best] rows (coalesced). Phase 3: coalesced z_q write + loss. ----
__global__ __launch_bounds__(256, 4)
void resolve_kernel(const float* __restrict__ z, const float* __restrict__ W,
                    const uint2* __restrict__ part,
                    float* __restrict__ zq, float* __restrict__ loss,
                    float* __restrict__ ind)
{
    __shared__ float wq[16 * 260];    // 16.6 KB, W[best] rows [pos_local][dim]
    __shared__ int   best[16];
    __shared__ float lred[4];

    const int t = threadIdx.x, w = t >> 6, lane = t & 63;
    const int pos0 = blockIdx.x * 16;
    const int b = pos0 >> 10, s0 = pos0 & 1023;

    // ---- phase 1: wave w resolves positions w*4 .. w*4+3 ----
#pragma unroll
    for (int i = 0; i < 4; ++i) {
        const int pl = w * 4 + i;
        const int p  = pos0 + pl;
        uint2 rec = part[(size_t)p * 16 + (lane & 15)];   // lanes 16+ duplicate
        unsigned k1 = rec.x, k2 = rec.y;

        unsigned kmax = (k1 > k2) ? k1 : k2;
#pragma unroll
        for (int off = 1; off < 64; off <<= 1) {
            unsigned o = (unsigned)__shfl_xor((int)kmax, off, 64);
            kmax = (o > kmax) ? o : kmax;
        }
        const float vmax = ord2f(kmax & 0xFFFFE000u);
        const float thr  = vmax - MARGIN;

        // count in-margin candidates (val_hi = upper bound of truncated value)
        int cl = 0;
        if (lane < 16) {
            float h1 = ord2f((k1 & 0xFFFFE000u) + 0x2000u);
            float h2 = ord2f((k2 & 0xFFFFE000u) + 0x2000u);
            cl = ((h1 >= thr) ? 1 : 0) + ((h2 >= thr) ? 1 : 0);
        }
#pragma unroll
        for (int off = 1; off < 64; off <<= 1) cl += __shfl_xor(cl, off, 64);

        int bi;
        if (cl <= 1) {
            bi = 8191 - (int)(kmax & 8191u);   // key max == argmax w/ min-idx tie
        } else {
            // exact fp32 refine (identical arithmetic to R4..R6, which passed)
            const float* zp = z + (size_t)b * 262144 + (p & 1023);
            float zf0 = zp[(size_t)(lane * 4 + 0) * 1024];
            float zf1 = zp[(size_t)(lane * 4 + 1) * 1024];
            float zf2 = zp[(size_t)(lane * 4 + 2) * 1024];
            float zf3 = zp[(size_t)(lane * 4 + 3) * 1024];
            float bv = -INFINITY; bi = 0x7FFFFFFF;
            for (int s16 = 0; s16 < 16; ++s16) {
                unsigned kk[2];
                kk[0] = (unsigned)__shfl((int)k1, s16, 64);
                kk[1] = (unsigned)__shfl((int)k2, s16, 64);
#pragma unroll
                for (int h = 0; h < 2; ++h) {
                    float vh = ord2f((kk[h] & 0xFFFFE000u) + 0x2000u);
                    if (vh < thr) continue;            // wave-uniform
                    int c = 8191 - (int)(kk[h] & 8191u);
                    float4 wf = *(const float4*)&W[(size_t)c * 256 + lane * 4];
                    float d = zf0 * wf.x + zf1 * wf.y + zf2 * wf.z + zf3 * wf.w;
#pragma unroll
                    for (int off = 1; off < 64; off <<= 1) d += __shfl_xor(d, off, 64);
                    if (d > bv || (d == bv && c < bi)) { bv = d; bi = c; }
                }
            }
        }
        if (lane == 0) { best[pl] = bi; ind[p] = (float)bi; }
    }
    __syncthreads();

    // ---- phase 2: stage W[best[r]] rows; 16 thr/row, 64B+ segments ----
    {
        int r = t >> 4, c = t & 15;
#pragma unroll
        for (int j = 0; j < 4; ++j) {
            int d = c * 4 + j * 64;
            *(float4*)&wq[r * 260 + d] = *(const float4*)&W[(size_t)best[r] * 256 + d];
        }
    }
    __syncthreads();

    // ---- phase 3: coalesced z_q + loss; sl = position, dg = dim group ----
    {
        int sl = t & 15, dg = t >> 4;
        float ls = 0.f;
#pragma unroll
        for (int it = 0; it < 4; ++it) {
            int d = it * 64 + dg * 4;
            float4 wv = *(const float4*)&wq[sl * 260 + d];
            const float* zp = z  + (size_t)b * 262144 + (size_t)d * 1024 + s0 + sl;
            float*       qp = zq + (size_t)b * 262144 + (size_t)d * 1024 + s0 + sl;
            float z0 = zp[0], z1 = zp[1024], z2 = zp[2048], z3 = zp[3072];
            qp[0] = wv.x; qp[1024] = wv.y; qp[2048] = wv.z; qp[3072] = wv.w;
            float d0 = wv.x - z0, d1 = wv.y - z1, d2 = wv.z - z2, d3 = wv.w - z3;
            ls += d0 * d0 + d1 * d1 + d2 * d2 + d3 * d3;
        }
#pragma unroll
        for (int off = 1; off < 64; off <<= 1) ls += __shfl_xor(ls, off, 64);
        if (lane == 0) lred[w] = ls;
    }
    __syncthreads();
    if (t == 0)
        atomicAdd(loss, (lred[0] + lred[1] + lred[2] + lred[3]) * (2.25f / 2097152.0f));
}

// ================= fallback (R1 fp32 kernel) if ws too small =================
#define TP 16
#define ZPAD 260
#define WPAD 36
__global__ __launch_bounds__(256, 2)
void vq_kernel(const float* __restrict__ z, const float* __restrict__ W,
               float* __restrict__ zq, float* __restrict__ loss,
               float* __restrict__ ind)
{
    __shared__ float zs[TP * ZPAD];
    __shared__ float ws[256 * WPAD];
    __shared__ int   best[TP];
    __shared__ float lred[4];
    const int t = threadIdx.x, w = t >> 6, lane = t & 63, cg = t & 63;
    const int pos_base = blockIdx.x * TP;
    const int b = pos_base >> 10, s0 = pos_base & 1023;
    const float* zb = z + (size_t)b * 262144 + s0;
    { int p = t & 15, dg = t >> 4;
      for (int i = 0; i < 16; ++i) { int d = i * 16 + dg; zs[p * ZPAD + d] = zb[(size_t)d * 1024 + p]; } }
    float maxv[4]; int maxi[4];
#pragma unroll
    for (int i = 0; i < 4; ++i) { maxv[i] = -INFINITY; maxi[i] = 0; }
    for (int cc = 0; cc < 32; ++cc) {
        float acc[4][4];
#pragma unroll
        for (int i = 0; i < 4; ++i)
#pragma unroll
            for (int j = 0; j < 4; ++j) acc[i][j] = 0.0f;
        for (int kp = 0; kp < 8; ++kp) {
            __syncthreads();
#pragma unroll
            for (int i = 0; i < 8; ++i) {
                int f = i * 256 + t, code = f >> 3, k4 = f & 7;
                float4 v = *(const float4*)&W[(size_t)(cc * 256 + code) * 256 + kp * 32 + k4 * 4];
                *(float4*)&ws[code * WPAD + k4 * 4] = v;
            }
            __syncthreads();
#pragma unroll
            for (int k4 = 0; k4 < 8; ++k4) {
                float4 zf[4], wf[4];
#pragma unroll
                for (int i = 0; i < 4; ++i) zf[i] = *(const float4*)&zs[(w * 4 + i) * ZPAD + kp * 32 + k4 * 4];
#pragma unroll
                for (int j = 0; j < 4; ++j) wf[j] = *(const float4*)&ws[(cg + 64 * j) * WPAD + k4 * 4];
#pragma unroll
                for (int i = 0; i < 4; ++i)
#pragma unroll
                    for (int j = 0; j < 4; ++j) {
                        acc[i][j] += zf[i].x * wf[j].x; acc[i][j] += zf[i].y * wf[j].y;
                        acc[i][j] += zf[i].z * wf[j].z; acc[i][j] += zf[i].w * wf[j].w;
                    }
            }
        }
#pragma unroll
        for (int i = 0; i < 4; ++i)
#pragma unroll
            for (int j = 0; j < 4; ++j) {
                int code = cc * 256 + cg + 64 * j; float v = acc[i][j];
                if (v > maxv[i] || (v == maxv[i] && code < maxi[i])) { maxv[i] = v; maxi[i] = code; }
            }
    }
#pragma unroll
    for (int i = 0; i < 4; ++i) {
        float v = maxv[i]; int idx = maxi[i];
        for (int off = 32; off > 0; off >>= 1) {
            float ov = __shfl_down(v, off, 64); int oi = __shfl_down(idx, off, 64);
            if (ov > v || (ov == v && oi < idx)) { v = ov; idx = oi; }
        }
        if (lane == 0) { int p = w * 4 + i; best[p] = idx; ind[pos_base + p] = (float)idx; }
    }
    __syncthreads();
    float lsum = 0.0f;
    for (int p = 0; p < TP; ++p) {
        int bi = best[p];
        float wv = W[(size_t)bi * 256 + t];
        float zv = zs[p * ZPAD + t];
        float dd = wv - zv; lsum += dd * dd;
        zq[(size_t)b * 262144 + (size_t)t * 1024 + s0 + p] = wv;
    }
    for (int off = 32; off > 0; off >>= 1) lsum += __shfl_down(lsum, off, 64);
    if (lane == 0) lred[w] = lsum;
    __syncthreads();
    if (t == 0) atomicAdd(loss, (lred[0] + lred[1] + lred[2] + lred[3]) * (2.25f / 2097152.0f));
}

extern "C" void kernel_launch(void* const* d_in, const int* in_sizes, int n_in,
                              void* d_out, int out_size, void* d_ws, size_t ws_size,
                              hipStream_t stream) {
    const float* z = (const float*)d_in[0];
    const float* W = (const float*)d_in[1];
    float* out  = (float*)d_out;
    float* zq   = out;
    float* loss = out + 2097152;
    float* ind  = out + 2097153;

    if (ws_size >= (size_t)10 * 1024 * 1024) {
        unsigned short* zbuf = (unsigned short*)d_ws;                    // 4 MB
        unsigned short* wbuf = zbuf + 2097152;                           // 4 MB
        uint2* part = (uint2*)((char*)d_ws + (size_t)8 * 1024 * 1024);   // 1 MB
        convert_kernel<<<2560, 256, 0, stream>>>(W, z, wbuf, zbuf, loss);
        gemm_argmax_kernel<<<dim3(64, 4), 512, 0, stream>>>(zbuf, wbuf, part);
        resolve_kernel<<<512, 256, 0, stream>>>(z, W, part, zq, loss, ind);
    } else {
        hipMemsetAsync(loss, 0, sizeof(float), stream);
        vq_kernel<<<512, 256, 0, stream>>>(z, W, zq, loss, ind);
    }
}

// Round 8
// 129.429 us; speedup vs baseline: 1.9588x; 1.9588x over previous
//
#include <hip/hip_runtime.h>
#include <math.h>

// VQ-VAE quantize on MI355X.
// z: (8, 256, 32, 32) fp32 -> 8192 positions x 256 dims; W: (8192, 256) fp32.
// out: [z_q 2097152 fp32][loss 1 fp32][ind 8192 fp32-encoded ints]
//
// Pipeline: convert (W->bf16 + z->bf16 [pos][k] + loss=0, one launch),
// gemm_argmax (bf16 MFMA; A full-K in LDS behind ONE barrier; B panels in
//              PER-WAVE private LDS double-buffers staged by per-wave
//              global_load_lds + s_waitcnt vmcnt(4) -- ZERO K-loop barriers;
//              packed-key argmax, top-2 per (bn,wn) slot -> part[pos][16]),
// resolve (block per 16 positions: key-decode + rare exact fp32 refine,
//          W-row LDS staging so z_q/loss I/O is fully coalesced).

using short8  = __attribute__((ext_vector_type(8))) short;   // 8 bf16, 4 VGPRs
using floatx4 = __attribute__((ext_vector_type(4))) float;   // MFMA acc

#define MARGIN 0.5f
#define APAD   264    // As row stride in shorts: 528B; b128 reads 2-way = free

__device__ inline unsigned short f2bf(float x) {
    union { float f; unsigned u; } v; v.f = x;
    unsigned r = v.u + 0x7fffu + ((v.u >> 16) & 1u);   // round-to-nearest-even
    return (unsigned short)(r >> 16);
}
__device__ inline unsigned f2ord(float f) {             // monotone float->uint
    unsigned u = __float_as_uint(f);
    return (u & 0x80000000u) ? ~u : (u | 0x80000000u);
}
__device__ inline float ord2f(unsigned o) {
    return __uint_as_float((o & 0x80000000u) ? (o ^ 0x80000000u) : ~o);
}

// ---- pre-pass, fused: blocks <2048 convert W; blocks >=2048 convert z;
//      block 0 also zeroes the loss accumulator (in-stream order => safe) ----
__global__ void convert_kernel(const float* __restrict__ W, const float* __restrict__ z,
                               unsigned short* __restrict__ wb, unsigned short* __restrict__ zb,
                               float* __restrict__ loss) {
    if (blockIdx.x < 2048) {
        if (blockIdx.x == 0 && threadIdx.x == 0) *loss = 0.f;
        int i = blockIdx.x * 256 + threadIdx.x;
        float4 v = *(const float4*)&W[(size_t)i * 4];
        ushort4 o;
        o.x = f2bf(v.x); o.y = f2bf(v.y); o.z = f2bf(v.z); o.w = f2bf(v.w);
        *(ushort4*)&wb[(size_t)i * 4] = o;
    } else {
        __shared__ float tile[64 * 65];
        int blk = blockIdx.x - 2048;
        int b  = blk >> 6;
        int dt = (blk >> 4) & 3;
        int st = blk & 15;
        int dl = threadIdx.x >> 6, sl = threadIdx.x & 63;
#pragma unroll
        for (int i = 0; i < 16; ++i) {
            int d = i * 4 + dl;
            tile[sl * 65 + d] = z[(size_t)b * 262144 + (size_t)(dt * 64 + d) * 1024 + st * 64 + sl];
        }
        __syncthreads();
        int d2 = threadIdx.x & 63, sr = threadIdx.x >> 6;
#pragma unroll
        for (int i = 0; i < 16; ++i) {
            int s = i * 4 + sr;
            int pos = b * 1024 + st * 64 + s;
            zb[(size_t)pos * 256 + dt * 64 + d2] = f2bf(tile[s * 65 + d2]);
        }
    }
}

// ---- main: bf16 MFMA GEMM (128M x 2048N per block, K=256) + fused argmax ----
// grid (64 m-tiles, 4 n-splits), 512 thr (8 waves), 1 block/CU.
// Wave tile 64x64: wm = w>>2, wn = w&3. Panels pc 0..63: nc=pc>>3, kp=pc&7.
// A: full-K LDS tile, ONE barrier, read-only afterwards.
// B: per-wave private 2x4KB LDS double-buffer; each wave stages its own
//    64-row x 32-k slice with 4 global_load_lds per panel and waits with
//    s_waitcnt vmcnt(4) (pc+1's 4 loads stay in flight). No barriers.
// Argmax keys: key = (ord(v) & ~8191) | (8191 - n) -> umax == argmax/min-idx.
__global__ __launch_bounds__(512, 2)
void gemm_argmax_kernel(const unsigned short* __restrict__ zb,
                        const unsigned short* __restrict__ wb,
                        uint2* __restrict__ part)
{
    __shared__ unsigned short As[128 * APAD];       // 67.6 KB
    __shared__ unsigned short Bs[8 * 2 * 2048];     // 64 KB: [wave][buf][64r x 32k]

    const int t  = threadIdx.x;
    const int bm = blockIdx.x, bn = blockIdx.y;
    const int w  = t >> 6, lane = t & 63;
    const int wm = w >> 2, wn = w & 3;
    const int q  = lane >> 4, l15 = lane & 15;

    const unsigned short* wsrc = wb + (size_t)bn * 2048 * 256;
    const int grow0 = wn * 64;                      // wave's first code row in panel
    unsigned short* myB = &Bs[w * 4096];            // wave-private, shorts

    // prologue: stage panel 0 -> buf0, panel 1 -> buf1 (per-wave DMA)
#pragma unroll
    for (int pp = 0; pp < 2; ++pp) {
#pragma unroll
        for (int i = 0; i < 4; ++i) {
            int u = i * 64 + lane;
            int row = u >> 2, kq = u & 3;
            int ksw = (kq ^ ((row >> 1) & 3)) * 8;
            const unsigned short* g = wsrc + (size_t)(grow0 + row) * 256 + pp * 32 + ksw;
            __builtin_amdgcn_global_load_lds(
                (const __attribute__((address_space(1))) void*)g,
                (__attribute__((address_space(3))) void*)(myB + pp * 2048 + u * 8),
                16, 0, 0);
        }
    }

    // stage As: 128 rows x 256 k (coalesced 512B row segments)
    {
        const unsigned short* src = zb + (size_t)bm * 128 * 256;
#pragma unroll
        for (int i = 0; i < 8; ++i) {
            int u = i * 512 + t;
            int row = u >> 5, c8 = (u & 31) * 8;
            *(short8*)(&As[row * APAD + c8]) = *(const short8*)(src + row * 256 + c8);
        }
    }
    __syncthreads();   // the ONLY barrier (drains everything incl. prologue DMA)

    unsigned kkey[4][4];
    floatx4  acc[4][4];
#pragma unroll
    for (int im = 0; im < 4; ++im)
#pragma unroll
        for (int r = 0; r < 4; ++r) {
            kkey[im][r] = 0u;
            floatx4 zz = {0.f, 0.f, 0.f, 0.f};
            acc[im][r] = zz;
        }

#pragma unroll 8
    for (int pc = 0; pc < 64; ++pc) {
        const int cur = pc & 1, kp = pc & 7;

        // ensure this buffer's 4 DMA loads have landed (next panel's 4 may
        // stay in flight) -- per-wave, no barrier
        asm volatile("s_waitcnt vmcnt(4)" ::: "memory");

        short8 af[4], bfr[4];
#pragma unroll
        for (int im = 0; im < 4; ++im)
            af[im] = *(const short8*)&As[(wm * 64 + im * 16 + l15) * APAD + kp * 32 + q * 8];
#pragma unroll
        for (int in = 0; in < 4; ++in) {
            int row = in * 16 + l15;
            bfr[in] = *(const short8*)(myB + cur * 2048 + row * 32 + (q ^ ((row >> 1) & 3)) * 8);
        }
#pragma unroll
        for (int im = 0; im < 4; ++im)
#pragma unroll
            for (int in = 0; in < 4; ++in)
                acc[im][in] = __builtin_amdgcn_mfma_f32_16x16x32_bf16(
                    af[im], bfr[in], acc[im][in], 0, 0, 0);

        // refill the just-consumed buffer with panel pc+2 (reads of it are
        // already complete in registers; DMA data returns much later)
        if (pc < 62) {
            const int np = pc + 2, nnc = np >> 3, nkp = np & 7;
#pragma unroll
            for (int i = 0; i < 4; ++i) {
                int u = i * 64 + lane;
                int row = u >> 2, kq = u & 3;
                int ksw = (kq ^ ((row >> 1) & 3)) * 8;
                const unsigned short* g =
                    wsrc + (size_t)(nnc * 256 + grow0 + row) * 256 + nkp * 32 + ksw;
                __builtin_amdgcn_global_load_lds(
                    (const __attribute__((address_space(1))) void*)g,
                    (__attribute__((address_space(3))) void*)(myB + cur * 2048 + u * 8),
                    16, 0, 0);
            }
        }

        // end of a 256-code chunk: tournament over in, one key per (im,r)
        if ((pc & 7) == 7) {
            const int nc = pc >> 3;
            const int nbase = bn * 2048 + nc * 256 + wn * 64 + l15;
#pragma unroll
            for (int im = 0; im < 4; ++im)
#pragma unroll
                for (int r = 0; r < 4; ++r) {
                    float bv = acc[im][0][r];
                    int   bi = nbase;
#pragma unroll
                    for (int in = 1; in < 4; ++in) {
                        float v = acc[im][in][r];
                        int   n = nbase + in * 16;
                        bi = (v > bv) ? n : bi;
                        bv = (v > bv) ? v : bv;
                    }
                    unsigned key = (f2ord(bv) & 0xFFFFE000u) | (8191u - (unsigned)bi);
                    kkey[im][r] = (key > kkey[im][r]) ? key : kkey[im][r];
#pragma unroll
                    for (int in = 0; in < 4; ++in) acc[im][in][r] = 0.f;
                }
        }
    }

    // top-2 key merge across the 16 lanes sharing each m-row
#pragma unroll
    for (int im = 0; im < 4; ++im)
#pragma unroll
        for (int r = 0; r < 4; ++r) {
            unsigned k1 = kkey[im][r], k2 = 0u;
#pragma unroll
            for (int off = 1; off < 16; off <<= 1) {
                unsigned o1 = (unsigned)__shfl_xor((int)k1, off, 64);
                unsigned o2 = (unsigned)__shfl_xor((int)k2, off, 64);
                unsigned hi = (k1 > o1) ? k1 : o1;
                unsigned lo = (k1 > o1) ? o1 : k1;
                unsigned s2 = (k2 > o2) ? k2 : o2;
                k1 = hi;
                k2 = (lo > s2) ? lo : s2;
            }
            if (l15 == 0) {
                int pos = bm * 128 + wm * 64 + im * 16 + q * 4 + r;
                part[(size_t)pos * 16 + bn * 4 + wn] = make_uint2(k1, k2);
            }
        }
}

// ---- resolve: block per 16 positions (512 blocks). Phase 1: wave-parallel
// key-decode argmax over 16 slots, rare exact fp32 refine. Phase 2: stage
// W[best] rows (coalesced). Phase 3: coalesced z_q write + loss. ----
__global__ __launch_bounds__(256, 4)
void resolve_kernel(const float* __restrict__ z, const float* __restrict__ W,
                    const uint2* __restrict__ part,
                    float* __restrict__ zq, float* __restrict__ loss,
                    float* __restrict__ ind)
{
    __shared__ float wq[16 * 260];    // 16.6 KB, W[best] rows [pos_local][dim]
    __shared__ int   best[16];
    __shared__ float lred[4];

    const int t = threadIdx.x, w = t >> 6, lane = t & 63;
    const int pos0 = blockIdx.x * 16;
    const int b = pos0 >> 10, s0 = pos0 & 1023;

    // ---- phase 1: wave w resolves positions w*4 .. w*4+3 ----
#pragma unroll
    for (int i = 0; i < 4; ++i) {
        const int pl = w * 4 + i;
        const int p  = pos0 + pl;
        uint2 rec = part[(size_t)p * 16 + (lane & 15)];   // lanes 16+ duplicate
        unsigned k1 = rec.x, k2 = rec.y;

        unsigned kmax = (k1 > k2) ? k1 : k2;
#pragma unroll
        for (int off = 1; off < 64; off <<= 1) {
            unsigned o = (unsigned)__shfl_xor((int)kmax, off, 64);
            kmax = (o > kmax) ? o : kmax;
        }
        const float vmax = ord2f(kmax & 0xFFFFE000u);
        const float thr  = vmax - MARGIN;

        // count in-margin candidates (val_hi = upper bound of truncated value)
        int cl = 0;
        if (lane < 16) {
            float h1 = ord2f((k1 & 0xFFFFE000u) + 0x2000u);
            float h2 = ord2f((k2 & 0xFFFFE000u) + 0x2000u);
            cl = ((h1 >= thr) ? 1 : 0) + ((h2 >= thr) ? 1 : 0);
        }
#pragma unroll
        for (int off = 1; off < 64; off <<= 1) cl += __shfl_xor(cl, off, 64);

        int bi;
        if (cl <= 1) {
            bi = 8191 - (int)(kmax & 8191u);   // key max == argmax w/ min-idx tie
        } else {
            // exact fp32 refine (identical arithmetic to R4..R6, which passed)
            const float* zp = z + (size_t)b * 262144 + (p & 1023);
            float zf0 = zp[(size_t)(lane * 4 + 0) * 1024];
            float zf1 = zp[(size_t)(lane * 4 + 1) * 1024];
            float zf2 = zp[(size_t)(lane * 4 + 2) * 1024];
            float zf3 = zp[(size_t)(lane * 4 + 3) * 1024];
            float bv = -INFINITY; bi = 0x7FFFFFFF;
            for (int s16 = 0; s16 < 16; ++s16) {
                unsigned kk[2];
                kk[0] = (unsigned)__shfl((int)k1, s16, 64);
                kk[1] = (unsigned)__shfl((int)k2, s16, 64);
#pragma unroll
                for (int h = 0; h < 2; ++h) {
                    float vh = ord2f((kk[h] & 0xFFFFE000u) + 0x2000u);
                    if (vh < thr) continue;            // wave-uniform
                    int c = 8191 - (int)(kk[h] & 8191u);
                    float4 wf = *(const float4*)&W[(size_t)c * 256 + lane * 4];
                    float d = zf0 * wf.x + zf1 * wf.y + zf2 * wf.z + zf3 * wf.w;
#pragma unroll
                    for (int off = 1; off < 64; off <<= 1) d += __shfl_xor(d, off, 64);
                    if (d > bv || (d == bv && c < bi)) { bv = d; bi = c; }
                }
            }
        }
        if (lane == 0) { best[pl] = bi; ind[p] = (float)bi; }
    }
    __syncthreads();

    // ---- phase 2: stage W[best[r]] rows; 16 thr/row, 64B+ segments ----
    {
        int r = t >> 4, c = t & 15;
#pragma unroll
        for (int j = 0; j < 4; ++j) {
            int d = c * 4 + j * 64;
            *(float4*)&wq[r * 260 + d] = *(const float4*)&W[(size_t)best[r] * 256 + d];
        }
    }
    __syncthreads();

    // ---- phase 3: coalesced z_q + loss; sl = position, dg = dim group ----
    {
        int sl = t & 15, dg = t >> 4;
        float ls = 0.f;
#pragma unroll
        for (int it = 0; it < 4; ++it) {
            int d = it * 64 + dg * 4;
            float4 wv = *(const float4*)&wq[sl * 260 + d];
            const float* zp = z  + (size_t)b * 262144 + (size_t)d * 1024 + s0 + sl;
            float*       qp = zq + (size_t)b * 262144 + (size_t)d * 1024 + s0 + sl;
            float z0 = zp[0], z1 = zp[1024], z2 = zp[2048], z3 = zp[3072];
            qp[0] = wv.x; qp[1024] = wv.y; qp[2048] = wv.z; qp[3072] = wv.w;
            float d0 = wv.x - z0, d1 = wv.y - z1, d2 = wv.z - z2, d3 = wv.w - z3;
            ls += d0 * d0 + d1 * d1 + d2 * d2 + d3 * d3;
        }
#pragma unroll
        for (int off = 1; off < 64; off <<= 1) ls += __shfl_xor(ls, off, 64);
        if (lane == 0) lred[w] = ls;
    }
    __syncthreads();
    if (t == 0)
        atomicAdd(loss, (lred[0] + lred[1] + lred[2] + lred[3]) * (2.25f / 2097152.0f));
}

// ================= fallback (R1 fp32 kernel) if ws too small =================
#define TP 16
#define ZPAD 260
#define WPAD 36
__global__ __launch_bounds__(256, 2)
void vq_kernel(const float* __restrict__ z, const float* __restrict__ W,
               float* __restrict__ zq, float* __restrict__ loss,
               float* __restrict__ ind)
{
    __shared__ float zs[TP * ZPAD];
    __shared__ float ws[256 * WPAD];
    __shared__ int   best[TP];
    __shared__ float lred[4];
    const int t = threadIdx.x, w = t >> 6, lane = t & 63, cg = t & 63;
    const int pos_base = blockIdx.x * TP;
    const int b = pos_base >> 10, s0 = pos_base & 1023;
    const float* zb = z + (size_t)b * 262144 + s0;
    { int p = t & 15, dg = t >> 4;
      for (int i = 0; i < 16; ++i) { int d = i * 16 + dg; zs[p * ZPAD + d] = zb[(size_t)d * 1024 + p]; } }
    float maxv[4]; int maxi[4];
#pragma unroll
    for (int i = 0; i < 4; ++i) { maxv[i] = -INFINITY; maxi[i] = 0; }
    for (int cc = 0; cc < 32; ++cc) {
        float acc[4][4];
#pragma unroll
        for (int i = 0; i < 4; ++i)
#pragma unroll
            for (int j = 0; j < 4; ++j) acc[i][j] = 0.0f;
        for (int kp = 0; kp < 8; ++kp) {
            __syncthreads();
#pragma unroll
            for (int i = 0; i < 8; ++i) {
                int f = i * 256 + t, code = f >> 3, k4 = f & 7;
                float4 v = *(const float4*)&W[(size_t)(cc * 256 + code) * 256 + kp * 32 + k4 * 4];
                *(float4*)&ws[code * WPAD + k4 * 4] = v;
            }
            __syncthreads();
#pragma unroll
            for (int k4 = 0; k4 < 8; ++k4) {
                float4 zf[4], wf[4];
#pragma unroll
                for (int i = 0; i < 4; ++i) zf[i] = *(const float4*)&zs[(w * 4 + i) * ZPAD + kp * 32 + k4 * 4];
#pragma unroll
                for (int j = 0; j < 4; ++j) wf[j] = *(const float4*)&ws[(cg + 64 * j) * WPAD + k4 * 4];
#pragma unroll
                for (int i = 0; i < 4; ++i)
#pragma unroll
                    for (int j = 0; j < 4; ++j) {
                        acc[i][j] += zf[i].x * wf[j].x; acc[i][j] += zf[i].y * wf[j].y;
                        acc[i][j] += zf[i].z * wf[j].z; acc[i][j] += zf[i].w * wf[j].w;
                    }
            }
        }
#pragma unroll
        for (int i = 0; i < 4; ++i)
#pragma unroll
            for (int j = 0; j < 4; ++j) {
                int code = cc * 256 + cg + 64 * j; float v = acc[i][j];
                if (v > maxv[i] || (v == maxv[i] && code < maxi[i])) { maxv[i] = v; maxi[i] = code; }
            }
    }
#pragma unroll
    for (int i = 0; i < 4; ++i) {
        float v = maxv[i]; int idx = maxi[i];
        for (int off = 32; off > 0; off >>= 1) {
            float ov = __shfl_down(v, off, 64); int oi = __shfl_down(idx, off, 64);
            if (ov > v || (ov == v && oi < idx)) { v = ov; idx = oi; }
        }
        if (lane == 0) { int p = w * 4 + i; best[p] = idx; ind[pos_base + p] = (float)idx; }
    }
    __syncthreads();
    float lsum = 0.0f;
    for (int p = 0; p < TP; ++p) {
        int bi = best[p];
        float wv = W[(size_t)bi * 256 + t];
        float zv = zs[p * ZPAD + t];
        float dd = wv - zv; lsum += dd * dd;
        zq[(size_t)b * 262144 + (size_t)t * 1024 + s0 + p] = wv;
    }
    for (int off = 32; off > 0; off >>= 1) lsum += __shfl_down(lsum, off, 64);
    if (lane == 0) lred[w] = lsum;
    __syncthreads();
    if (t == 0) atomicAdd(loss, (lred[0] + lred[1] + lred[2] + lred[3]) * (2.25f / 2097152.0f));
}

extern "C" void kernel_launch(void* const* d_in, const int* in_sizes, int n_in,
                              void* d_out, int out_size, void* d_ws, size_t ws_size,
                              hipStream_t stream) {
    const float* z = (const float*)d_in[0];
    const float* W = (const float*)d_in[1];
    float* out  = (float*)d_out;
    float* zq   = out;
    float* loss = out + 2097152;
    float* ind  = out + 2097153;

    if (ws_size >= (size_t)10 * 1024 * 1024) {
        unsigned short* zbuf = (unsigned short*)d_ws;                    // 4 MB
        unsigned short* wbuf = zbuf + 2097152;                           // 4 MB
        uint2* part = (uint2*)((char*)d_ws + (size_t)8 * 1024 * 1024);   // 1 MB
        convert_kernel<<<2560, 256, 0, stream>>>(W, z, wbuf, zbuf, loss);
        gemm_argmax_kernel<<<dim3(64, 4), 512, 0, stream>>>(zbuf, wbuf, part);
        resolve_kernel<<<512, 256, 0, stream>>>(z, W, part, zq, loss, ind);
    } else {
        hipMemsetAsync(loss, 0, sizeof(float), stream);
        vq_kernel<<<512, 256, 0, stream>>>(z, W, zq, loss, ind);
    }
}